// Round 6
// baseline (337.062 us; speedup 1.0000x reference)
//
#include <hip/hip_runtime.h>
#include <stdint.h>

#define DEV __device__ __forceinline__

typedef float f32x4 __attribute__((ext_vector_type(4)));
typedef __bf16 bf16x8 __attribute__((ext_vector_type(8)));
typedef short short8 __attribute__((ext_vector_type(8)));
typedef short short4v __attribute__((ext_vector_type(4)));

DEV unsigned short f2bf(float f) {
    union { float f; unsigned u; } c; c.f = f;
    unsigned u = c.u;
    u += 0x7fffu + ((u >> 16) & 1u);   // round-to-nearest-even
    return (unsigned short)(u >> 16);
}
DEV float bf2f(unsigned short u) {
    union { unsigned u; float f; } c; c.u = ((unsigned)u) << 16; return c.f;
}
DEV void async_ld16(const void* g, void* l) {
    __builtin_amdgcn_global_load_lds(
        (const __attribute__((address_space(1))) unsigned int*)g,
        (__attribute__((address_space(3))) unsigned int*)l, 16, 0, 0);
}
DEV f32x4 mfma16(bf16x8 a, bf16x8 b, f32x4 c) {
    return __builtin_amdgcn_mfma_f32_16x16x32_bf16(a, b, c, 0, 0, 0);
}

// ---------------- k_prep: xb (token-major bf16) + xt (dim-major bf16) +
// Wt (de-interleaved transposed [3][1024][1024]) + s (fp32 col sums) --------
// blocks [0,2048): x tiles; [2048,2816): W tiles; [2816,2880): s
__global__ __launch_bounds__(256) void k_prep(const float* __restrict__ x,
                                              const float* __restrict__ W,
                                              unsigned short* __restrict__ xb,
                                              unsigned short* __restrict__ xt,
                                              unsigned short* __restrict__ Wt,
                                              float* __restrict__ s) {
    __shared__ float T[64][65];
    const int blk = blockIdx.x, t = threadIdx.x;
    if (blk < 2048) {
        int batch = blk >> 9, r512 = blk & 511;
        int t0 = (r512 >> 4) * 64, d0 = (r512 & 15) * 64;
        int rr = t >> 4, c4 = (t & 15) * 4;
        for (int i = 0; i < 4; i++) {
            int row = rr + i * 16;   // token within tile
            float4 v = *(const float4*)(x + (unsigned)(batch * 2048 + t0 + row) * 1024u + d0 + c4);
            T[row][c4] = v.x; T[row][c4 + 1] = v.y; T[row][c4 + 2] = v.z; T[row][c4 + 3] = v.w;
            short4v o;
            o[0] = (short)f2bf(v.x); o[1] = (short)f2bf(v.y);
            o[2] = (short)f2bf(v.z); o[3] = (short)f2bf(v.w);
            *(short4v*)(xb + (unsigned)(batch * 2048 + t0 + row) * 1024u + d0 + c4) = o;
        }
        __syncthreads();
        for (int i = 0; i < 4; i++) {
            int nrow = rr + i * 16;  // dim within tile
            short4v o;
            o[0] = (short)f2bf(T[c4 + 0][nrow]);
            o[1] = (short)f2bf(T[c4 + 1][nrow]);
            o[2] = (short)f2bf(T[c4 + 2][nrow]);
            o[3] = (short)f2bf(T[c4 + 3][nrow]);
            *(short4v*)(xt + (unsigned)(batch * 1024 + d0 + nrow) * 2048u + t0 + c4) = o;
        }
    } else if (blk < 2816) {
        int bx = blk - 2048;
        int k0 = (bx / 48) * 64, n0 = (bx % 48) * 64;
        int rr = t >> 4, c4 = (t & 15) * 4;
        for (int i = 0; i < 4; i++) {
            int row = rr + i * 16;   // k within tile
            float4 v = *(const float4*)(W + (unsigned)(k0 + row) * 3072u + n0 + c4);
            T[row][c4] = v.x; T[row][c4 + 1] = v.y; T[row][c4 + 2] = v.z; T[row][c4 + 3] = v.w;
        }
        __syncthreads();
        for (int i = 0; i < 4; i++) {
            int ncol = rr + i * 16;
            int n = n0 + ncol;
            int which = n % 3;
            int oc = (n / 192) * 64 + (n % 192) / 3;
            short4v o;
            o[0] = (short)f2bf(T[c4 + 0][ncol]);
            o[1] = (short)f2bf(T[c4 + 1][ncol]);
            o[2] = (short)f2bf(T[c4 + 2][ncol]);
            o[3] = (short)f2bf(T[c4 + 3][ncol]);
            *(short4v*)(Wt + (unsigned)which * 1048576u + (unsigned)oc * 1024u + k0 + c4) = o;
        }
    } else {
        int idx = blk - 2816;        // 64 blocks: 4 batches x 16 col-groups
        int batch = idx >> 4, dg = idx & 15;
        int col = dg * 64 + (t & 63), rg = t >> 6;
        float a = 0.0f;
        for (int r = rg * 512; r < rg * 512 + 512; r++)
            a += x[(unsigned)(batch * 2048 + r) * 1024u + col];
        ((float*)T)[rg * 64 + (t & 63)] = a;
        __syncthreads();
        if (t < 64) {
            float v = ((float*)T)[t] + ((float*)T)[64 + t] +
                      ((float*)T)[128 + t] + ((float*)T)[192 + t];
            s[batch * 1024 + dg * 64 + t] = v;
        }
    }
}

// ---------------- k_q: Qs = (x Wq + bq) * 32, packed row-major [b][2048][1024]
// Swapped operands (A=Wt rows -> m=outcol) so lane's 4 acc values are 4
// consecutive outcols -> packed uint2 stores.
__global__ __launch_bounds__(256, 2) void k_q(const unsigned short* __restrict__ Wt,
                                              const unsigned short* __restrict__ xb,
                                              const float* __restrict__ bias,
                                              unsigned short* __restrict__ Qs) {
    __shared__ __align__(16) unsigned short As[128 * 64];
    __shared__ __align__(16) unsigned short Bs[128 * 64];
    const int m0 = blockIdx.x * 128;   // outcols (8 tiles)
    const int n0 = blockIdx.y * 128;   // tokens (64 tiles)
    const int wave = threadIdx.x >> 6, lane = threadIdx.x & 63;
    const int wm = (wave & 1) * 64, wn = (wave >> 1) * 64;
    const int lan15 = lane & 15, quad = lane >> 4;
    f32x4 acc[4][4] = {};
    const int slr = wave * 32 + (lane >> 3);
    const int scs = lane & 7;

    for (int kt = 0; kt < 16; kt++) {
        __syncthreads();
        for (int i = 0; i < 4; i++) {
            int lr = slr + i * 8;
            int c = scs ^ (lr & 7);
            async_ld16(Wt + (unsigned)(m0 + lr) * 1024u + kt * 64 + c * 8,
                       (void*)(As + (wave * 32 + i * 8) * 64));
            async_ld16(xb + (unsigned)(n0 + lr) * 1024u + kt * 64 + c * 8,
                       (void*)(Bs + (wave * 32 + i * 8) * 64));
        }
        __syncthreads();
        for (int ks = 0; ks < 2; ks++) {
            bf16x8 af[4], bfr[4];
            int c0 = ks * 4 + quad;
            for (int tm = 0; tm < 4; tm++) {
                int row = wm + tm * 16 + lan15;
                af[tm] = *(const bf16x8*)(As + row * 64 + (c0 ^ (row & 7)) * 8);
            }
            for (int tn = 0; tn < 4; tn++) {
                int row = wn + tn * 16 + lan15;
                bfr[tn] = *(const bf16x8*)(Bs + row * 64 + (c0 ^ (row & 7)) * 8);
            }
            for (int tm = 0; tm < 4; tm++)
                for (int tn = 0; tn < 4; tn++)
                    acc[tm][tn] = mfma16(af[tm], bfr[tn], acc[tm][tn]);
        }
    }

    for (int tm = 0; tm < 4; tm++) {
        int oc = m0 + wm + tm * 16 + quad * 4;      // aligned-4, within one head
        int h = oc >> 6, dd = oc & 63;
        float b0 = bias[h * 192 + (dd + 0) * 3];
        float b1 = bias[h * 192 + (dd + 1) * 3];
        float b2 = bias[h * 192 + (dd + 2) * 3];
        float b3 = bias[h * 192 + (dd + 3) * 3];
        for (int tn = 0; tn < 4; tn++) {
            int token = n0 + wn + tn * 16 + lan15;
            unsigned bb = (unsigned)(token >> 11), tl = (unsigned)(token & 2047);
            uint2 p;
            p.x = (unsigned)f2bf((acc[tm][tn][0] + b0) * 32.0f) |
                  ((unsigned)f2bf((acc[tm][tn][1] + b1) * 32.0f) << 16);
            p.y = (unsigned)f2bf((acc[tm][tn][2] + b2) * 32.0f) |
                  ((unsigned)f2bf((acc[tm][tn][3] + b3) * 32.0f) << 16);
            *(uint2*)(Qs + bb * 2097152u + tl * 1024u + oc) = p;
        }
    }
}

// ---------------- k_syrk: G_b = x_b^T x_b, bf16 out (64x128 tiles, K=2048) --
// Epilogue uses symmetry: writes D[m][n] at G[n][m..m+3] packed.
__global__ __launch_bounds__(256, 2) void k_syrk(const unsigned short* __restrict__ xt,
                                                 unsigned short* __restrict__ G) {
    __shared__ __align__(16) unsigned short As[64 * 64];
    __shared__ __align__(16) unsigned short Bs[128 * 64];
    const int b = blockIdx.z;
    const int i0 = blockIdx.x * 64, j0 = blockIdx.y * 128;
    const int wave = threadIdx.x >> 6, lane = threadIdx.x & 63;
    const int wm = (wave & 1) * 32, wn = (wave >> 1) * 64;
    const int lan15 = lane & 15, quad = lane >> 4;
    const unsigned xbase = (unsigned)b * 2097152u;
    f32x4 acc[2][4] = {};
    const int slrA = wave * 16 + (lane >> 3);
    const int slrB = wave * 32 + (lane >> 3);
    const int scs = lane & 7;

    for (int kt = 0; kt < 32; kt++) {
        __syncthreads();
        for (int i = 0; i < 2; i++) {
            int lr = slrA + i * 8;
            int c = scs ^ (lr & 7);
            async_ld16(xt + xbase + (unsigned)(i0 + lr) * 2048u + kt * 64 + c * 8,
                       (void*)(As + (wave * 16 + i * 8) * 64));
        }
        for (int i = 0; i < 4; i++) {
            int lr = slrB + i * 8;
            int c = scs ^ (lr & 7);
            async_ld16(xt + xbase + (unsigned)(j0 + lr) * 2048u + kt * 64 + c * 8,
                       (void*)(Bs + (wave * 32 + i * 8) * 64));
        }
        __syncthreads();
        for (int ks = 0; ks < 2; ks++) {
            bf16x8 af[2], bfr[4];
            int c0 = ks * 4 + quad;
            for (int tm = 0; tm < 2; tm++) {
                int row = wm + tm * 16 + lan15;
                af[tm] = *(const bf16x8*)(As + row * 64 + (c0 ^ (row & 7)) * 8);
            }
            for (int tn = 0; tn < 4; tn++) {
                int row = wn + tn * 16 + lan15;
                bfr[tn] = *(const bf16x8*)(Bs + row * 64 + (c0 ^ (row & 7)) * 8);
            }
            for (int tm = 0; tm < 2; tm++)
                for (int tn = 0; tn < 4; tn++)
                    acc[tm][tn] = mfma16(af[tm], bfr[tn], acc[tm][tn]);
        }
    }
    const unsigned gbase = (unsigned)b * 1048576u;
    for (int tm = 0; tm < 2; tm++) {
        int d1q = i0 + wm + tm * 16 + quad * 4;
        for (int tn = 0; tn < 4; tn++) {
            int d2 = j0 + wn + tn * 16 + lan15;
            uint2 p;
            p.x = (unsigned)f2bf(acc[tm][tn][0]) | ((unsigned)f2bf(acc[tm][tn][1]) << 16);
            p.y = (unsigned)f2bf(acc[tm][tn][2]) | ((unsigned)f2bf(acc[tm][tn][3]) << 16);
            *(uint2*)(G + gbase + (unsigned)d2 * 1024u + d1q) = p;
        }
    }
}

// ---------------- k_gv: GVt_b[vcol][r] = (G_b . Wv)[r][vcol] (transposed out)
__global__ __launch_bounds__(256, 2) void k_gv(const unsigned short* __restrict__ G,
                                               const unsigned short* __restrict__ Wt,
                                               unsigned short* __restrict__ GVt) {
    __shared__ __align__(16) unsigned short As[64 * 64];
    __shared__ __align__(16) unsigned short Bs[128 * 64];
    const int b = blockIdx.z;
    const int i0 = blockIdx.x * 64;    // r tile
    const int j0 = blockIdx.y * 128;   // vcol tile
    const int wave = threadIdx.x >> 6, lane = threadIdx.x & 63;
    const int wm = (wave & 1) * 32, wn = (wave >> 1) * 64;
    const int lan15 = lane & 15, quad = lane >> 4;
    const unsigned gbase = (unsigned)b * 1048576u;
    const unsigned short* Wv = Wt + 2097152u;   // which=2 plane
    f32x4 acc[2][4] = {};
    const int slrA = wave * 16 + (lane >> 3);
    const int slrB = wave * 32 + (lane >> 3);
    const int scs = lane & 7;

    for (int kt = 0; kt < 16; kt++) {
        __syncthreads();
        for (int i = 0; i < 2; i++) {
            int lr = slrA + i * 8;
            int c = scs ^ (lr & 7);
            async_ld16(G + gbase + (unsigned)(i0 + lr) * 1024u + kt * 64 + c * 8,
                       (void*)(As + (wave * 16 + i * 8) * 64));
        }
        for (int i = 0; i < 4; i++) {
            int lr = slrB + i * 8;
            int c = scs ^ (lr & 7);
            async_ld16(Wv + (unsigned)(j0 + lr) * 1024u + kt * 64 + c * 8,
                       (void*)(Bs + (wave * 32 + i * 8) * 64));
        }
        __syncthreads();
        for (int ks = 0; ks < 2; ks++) {
            bf16x8 af[2], bfr[4];
            int c0 = ks * 4 + quad;
            for (int tm = 0; tm < 2; tm++) {
                int row = wm + tm * 16 + lan15;
                af[tm] = *(const bf16x8*)(As + row * 64 + (c0 ^ (row & 7)) * 8);
            }
            for (int tn = 0; tn < 4; tn++) {
                int row = wn + tn * 16 + lan15;
                bfr[tn] = *(const bf16x8*)(Bs + row * 64 + (c0 ^ (row & 7)) * 8);
            }
            for (int tm = 0; tm < 2; tm++)
                for (int tn = 0; tn < 4; tn++)
                    acc[tm][tn] = mfma16(af[tm], bfr[tn], acc[tm][tn]);
        }
    }
    for (int tm = 0; tm < 2; tm++) {
        int rq = i0 + wm + tm * 16 + quad * 4;
        for (int tn = 0; tn < 4; tn++) {
            int vcol = j0 + wn + tn * 16 + lan15;
            uint2 p;
            p.x = (unsigned)f2bf(acc[tm][tn][0]) | ((unsigned)f2bf(acc[tm][tn][1]) << 16);
            p.y = (unsigned)f2bf(acc[tm][tn][2]) | ((unsigned)f2bf(acc[tm][tn][3]) << 16);
            *(uint2*)(GVt + gbase + (unsigned)vcol * 1024u + rq) = p;
        }
    }
}

// ---------------- k_mp: Mt[bh][d2][d1] = (Wk^T G Wv + bias corrections) -----
// block = (b,h); 4 waves k-split 256; LDS reduce; corrections from s (fp32).
__global__ __launch_bounds__(256) void k_mp(const unsigned short* __restrict__ Wt,
                                            const unsigned short* __restrict__ GVt,
                                            const float* __restrict__ s,
                                            const float* __restrict__ bias,
                                            unsigned short* __restrict__ Mt) {
    __shared__ __align__(16) float Ss[3 * 4096 + 128];
    const int bh = blockIdx.x, b = bh >> 4, h = bh & 15;
    const int wave = threadIdx.x >> 6, lane = threadIdx.x & 63;
    const int lan15 = lane & 15, quad = lane >> 4;
    const unsigned short* Wk = Wt + 1048576u + (unsigned)(h * 64) * 1024u;
    const unsigned short* GVh = GVt + (unsigned)b * 1048576u + (unsigned)(h * 64) * 1024u;
    f32x4 acc[4][4] = {};
    for (int it = 0; it < 8; it++) {
        int ko = wave * 256 + it * 32 + quad * 8;
        bf16x8 af[4], bfr[4];
        for (int mt = 0; mt < 4; mt++)
            af[mt] = *(const bf16x8*)(Wk + (unsigned)(mt * 16 + lan15) * 1024u + ko);
        for (int nt = 0; nt < 4; nt++)
            bfr[nt] = *(const bf16x8*)(GVh + (unsigned)(nt * 16 + lan15) * 1024u + ko);
        for (int mt = 0; mt < 4; mt++)
            for (int nt = 0; nt < 4; nt++)
                acc[mt][nt] = mfma16(af[mt], bfr[nt], acc[mt][nt]);
    }
    if (wave >= 1)
        for (int mt = 0; mt < 4; mt++)
            for (int nt = 0; nt < 4; nt++)
                *(f32x4*)(&Ss[(wave - 1) * 4096 + ((mt * 4 + nt) * 64 + lane) * 4]) = acc[mt][nt];

    // t1[d1] = Wk_h^T s_b, t2[d2] = Wv_h^T s_b  (threads 0..127)
    float* t1 = Ss + 12288;
    float* t2 = t1 + 64;
    const int tt = threadIdx.x;
    if (tt < 128) {
        int d = tt & 63;
        const unsigned short* wrow = Wt + (tt < 64 ? 1048576u : 2097152u) +
                                     (unsigned)(h * 64 + d) * 1024u;
        const float* sb = s + b * 1024;
        float a = 0.0f;
        for (int r = 0; r < 1024; r += 8) {
            short8 w8 = *(const short8*)(wrow + r);
            for (int j = 0; j < 8; j++)
                a += bf2f((unsigned short)w8[j]) * sb[r + j];
        }
        (tt < 64 ? t1 : t2)[d] = a;
    }
    __syncthreads();
    if (wave == 0) {
        for (int mt = 0; mt < 4; mt++)
            for (int nt = 0; nt < 4; nt++) {
                f32x4 m = acc[mt][nt];
                for (int w = 0; w < 3; w++) {
                    f32x4 p = *(const f32x4*)(&Ss[w * 4096 + ((mt * 4 + nt) * 64 + lane) * 4]);
                    m.x += p.x; m.y += p.y; m.z += p.z; m.w += p.w;
                }
                int d2 = nt * 16 + lan15;
                float bv = bias[h * 192 + d2 * 3 + 2];
                float tw = t2[d2];
                unsigned short v[4];
                for (int r = 0; r < 4; r++) {
                    int d1 = mt * 16 + quad * 4 + r;
                    float bk = bias[h * 192 + d1 * 3 + 1];
                    v[r] = f2bf(m[r] + t1[d1] * bv + bk * tw + 2048.0f * bk * bv);
                }
                uint2 p;
                p.x = (unsigned)v[0] | ((unsigned)v[1] << 16);
                p.y = (unsigned)v[2] | ((unsigned)v[3] << 16);
                *(uint2*)(Mt + (unsigned)bh * 4096u + (unsigned)d2 * 64u +
                          mt * 16 + quad * 4) = p;
            }
    }
}

// ---------------- k_out: out[bh][n][d2] = Qs[b][n][h*64+d1] . Mt[bh][d2][d1]
__global__ __launch_bounds__(256) void k_out(const unsigned short* __restrict__ Qs,
                                             const unsigned short* __restrict__ Mt,
                                             float* __restrict__ out) {
    const int bh = blockIdx.y, b = bh >> 4, h = bh & 15;
    const int wave = threadIdx.x >> 6, lane = threadIdx.x & 63;
    const int lan15 = lane & 15, quad = lane >> 4;
    const int t0w = blockIdx.x * 256 + wave * 64;
    f32x4 acc[4][4] = {};
#pragma unroll
    for (int ks = 0; ks < 2; ks++) {
        bf16x8 af[4], bfr[4];
        for (int mt = 0; mt < 4; mt++) {
            int tok = t0w + mt * 16 + lan15;
            af[mt] = *(const bf16x8*)(Qs + (unsigned)b * 2097152u + (unsigned)tok * 1024u +
                                      h * 64 + ks * 32 + quad * 8);
        }
        for (int nt = 0; nt < 4; nt++)
            bfr[nt] = *(const bf16x8*)(Mt + (unsigned)bh * 4096u +
                                       (unsigned)(nt * 16 + lan15) * 64u + ks * 32 + quad * 8);
        for (int mt = 0; mt < 4; mt++)
            for (int nt = 0; nt < 4; nt++)
                acc[mt][nt] = mfma16(af[mt], bfr[nt], acc[mt][nt]);
    }
    for (int mt = 0; mt < 4; mt++)
        for (int nt = 0; nt < 4; nt++)
            for (int r = 0; r < 4; r++)
                out[(unsigned)bh * 131072u + (unsigned)(t0w + mt * 16 + quad * 4 + r) * 64u +
                    nt * 16 + lan15] = acc[mt][nt][r];
}

extern "C" void kernel_launch(void* const* d_in, const int* in_sizes, int n_in,
                              void* d_out, int out_size, void* d_ws, size_t ws_size,
                              hipStream_t stream) {
    const float* x = (const float*)d_in[0];
    const float* W = (const float*)d_in[1];
    const float* b = (const float*)d_in[2];
    float* out = (float*)d_out;

    unsigned short* xb = (unsigned short*)d_ws;  // 8,388,608  [8192][1024] bf16
    unsigned short* xt = xb + 8388608;           // 8,388,608  [4][1024][2048] bf16
    unsigned short* Wt = xt + 8388608;           // 3,145,728  [3][1024][1024] bf16
    unsigned short* Qs = Wt + 3145728;           // 8,388,608  [4][2048][1024] bf16 (*32, +bias)
    unsigned short* G  = Qs + 8388608;           // 4,194,304  [4][1024][1024] bf16
    unsigned short* Mt = G + 4194304;            //   262,144  [64][64][64] bf16
    float* s = (float*)(Mt + 262144);            //     4,096  fp32
    unsigned short* GVt = xt;                    // alias: xt dead after k_syrk
    // total: 65,552,384 bytes (< 73.4 MB known-safe)

    k_prep<<<2880, 256, 0, stream>>>(x, W, xb, xt, Wt, s);
    k_q<<<dim3(8, 64), 256, 0, stream>>>(Wt, xb, b, Qs);
    k_syrk<<<dim3(16, 8, 4), 256, 0, stream>>>(xt, G);
    k_gv<<<dim3(16, 8, 4), 256, 0, stream>>>(G, Wt, GVt);
    k_mp<<<64, 256, 0, stream>>>(Wt, GVt, s, b, Mt);
    k_out<<<dim3(8, 64), 256, 0, stream>>>(Qs, Mt, out);
}

// Round 7
// 182.616 us; speedup vs baseline: 1.8457x; 1.8457x over previous
//
#include <hip/hip_runtime.h>
#include <stdint.h>

#define DEV __device__ __forceinline__

typedef float f32x4 __attribute__((ext_vector_type(4)));
typedef __bf16 bf16x8 __attribute__((ext_vector_type(8)));
typedef short short8 __attribute__((ext_vector_type(8)));
typedef short short4v __attribute__((ext_vector_type(4)));

DEV unsigned short f2bf(float f) {
    union { float f; unsigned u; } c; c.f = f;
    unsigned u = c.u;
    u += 0x7fffu + ((u >> 16) & 1u);   // round-to-nearest-even
    return (unsigned short)(u >> 16);
}
DEV void async_ld16(const void* g, void* l) {
    __builtin_amdgcn_global_load_lds(
        (const __attribute__((address_space(1))) unsigned int*)g,
        (__attribute__((address_space(3))) unsigned int*)l, 16, 0, 0);
}
DEV f32x4 mfma16(bf16x8 a, bf16x8 b, f32x4 c) {
    return __builtin_amdgcn_mfma_f32_16x16x32_bf16(a, b, c, 0, 0, 0);
}

// ---------------- k_prep: x->bf16 + W de-interleaved transpose --------------
// blocks [0,4096): x cvt; [4096,4864): W -> Wt[3][1024][1024]
__global__ __launch_bounds__(256) void k_prep(const float* __restrict__ x,
                                              const float* __restrict__ W,
                                              unsigned short* __restrict__ xb,
                                              unsigned short* __restrict__ Wt) {
    __shared__ float T[64][65];
    const int blk = blockIdx.x, t = threadIdx.x;
    if (blk < 4096) {
        int i = blk * 256 + t;
        const float4* xp = (const float4*)x;
        float4 a = xp[i * 2], b = xp[i * 2 + 1];
        short8 o;
        o[0] = (short)f2bf(a.x); o[1] = (short)f2bf(a.y);
        o[2] = (short)f2bf(a.z); o[3] = (short)f2bf(a.w);
        o[4] = (short)f2bf(b.x); o[5] = (short)f2bf(b.y);
        o[6] = (short)f2bf(b.z); o[7] = (short)f2bf(b.w);
        *(short8*)(xb + i * 8) = o;
    } else {
        int bx = blk - 4096;
        int k0 = (bx / 48) * 64, n0 = (bx % 48) * 64;
        int rr = t >> 4, c4 = (t & 15) * 4;
        for (int i = 0; i < 4; i++) {
            int row = rr + i * 16;
            float4 v = *(const float4*)(W + (unsigned)(k0 + row) * 3072u + n0 + c4);
            T[row][c4] = v.x; T[row][c4 + 1] = v.y; T[row][c4 + 2] = v.z; T[row][c4 + 3] = v.w;
        }
        __syncthreads();
        for (int i = 0; i < 4; i++) {
            int ncol = rr + i * 16;
            int n = n0 + ncol;
            int which = n % 3;
            int oc = (n / 192) * 64 + (n % 192) / 3;
            short4v o;
            o[0] = (short)f2bf(T[c4 + 0][ncol]);
            o[1] = (short)f2bf(T[c4 + 1][ncol]);
            o[2] = (short)f2bf(T[c4 + 2][ncol]);
            o[3] = (short)f2bf(T[c4 + 3][ncol]);
            *(short4v*)(Wt + (unsigned)which * 1048576u + (unsigned)oc * 1024u + k0 + c4) = o;
        }
    }
}

// ---------------- k_q: Qs[b][token][1024] = (x Wq + bq) * 32, packed --------
// Swapped operands (A=Wq rows -> m=outcol): lane's 4 accs = 4 consecutive
// outcols -> packed uint2 stores.
__global__ __launch_bounds__(256, 2) void k_q(const unsigned short* __restrict__ Wt,
                                              const unsigned short* __restrict__ xb,
                                              const float* __restrict__ bias,
                                              unsigned short* __restrict__ Qs) {
    __shared__ __align__(16) unsigned short As[128 * 64];
    __shared__ __align__(16) unsigned short Bs[128 * 64];
    const int m0 = blockIdx.x * 128;   // Q outcols
    const int n0 = blockIdx.y * 128;   // tokens
    const int wave = threadIdx.x >> 6, lane = threadIdx.x & 63;
    const int wm = (wave & 1) * 64, wn = (wave >> 1) * 64;
    const int lan15 = lane & 15, quad = lane >> 4;
    f32x4 acc[4][4] = {};
    const int slr = wave * 32 + (lane >> 3);
    const int scs = lane & 7;

    for (int kt = 0; kt < 16; kt++) {
        __syncthreads();
        for (int i = 0; i < 4; i++) {
            int lr = slr + i * 8;
            int c = scs ^ (lr & 7);
            async_ld16(Wt + (unsigned)(m0 + lr) * 1024u + kt * 64 + c * 8,
                       (void*)(As + (wave * 32 + i * 8) * 64));
            async_ld16(xb + (unsigned)(n0 + lr) * 1024u + kt * 64 + c * 8,
                       (void*)(Bs + (wave * 32 + i * 8) * 64));
        }
        __syncthreads();
        for (int ks = 0; ks < 2; ks++) {
            bf16x8 af[4], bfr[4];
            int c0 = ks * 4 + quad;
            for (int tm = 0; tm < 4; tm++) {
                int row = wm + tm * 16 + lan15;
                af[tm] = *(const bf16x8*)(As + row * 64 + (c0 ^ (row & 7)) * 8);
            }
            for (int tn = 0; tn < 4; tn++) {
                int row = wn + tn * 16 + lan15;
                bfr[tn] = *(const bf16x8*)(Bs + row * 64 + (c0 ^ (row & 7)) * 8);
            }
            for (int tm = 0; tm < 4; tm++)
                for (int tn = 0; tn < 4; tn++)
                    acc[tm][tn] = mfma16(af[tm], bfr[tn], acc[tm][tn]);
        }
    }

    for (int tm = 0; tm < 4; tm++) {
        int oc = m0 + wm + tm * 16 + quad * 4;      // aligned-4, within one head
        int h = oc >> 6, dd = oc & 63;
        float b0 = bias[h * 192 + (dd + 0) * 3];
        float b1 = bias[h * 192 + (dd + 1) * 3];
        float b2 = bias[h * 192 + (dd + 2) * 3];
        float b3 = bias[h * 192 + (dd + 3) * 3];
        for (int tn = 0; tn < 4; tn++) {
            int token = n0 + wn + tn * 16 + lan15;
            unsigned bb = (unsigned)(token >> 11), tl = (unsigned)(token & 2047);
            uint2 p;
            p.x = (unsigned)f2bf((acc[tm][tn][0] + b0) * 32.0f) |
                  ((unsigned)f2bf((acc[tm][tn][1] + b1) * 32.0f) << 16);
            p.y = (unsigned)f2bf((acc[tm][tn][2] + b2) * 32.0f) |
                  ((unsigned)f2bf((acc[tm][tn][3] + b3) * 32.0f) << 16);
            *(uint2*)(Qs + bb * 2097152u + tl * 1024u + oc) = p;
        }
    }
}

// ---------------- k_kv: K,V projections -> transposed [bh][d][n] ------------
// n0 in [0,2048): plane 1 (K) for n0<1024 else plane 2 (V). Uniform per block.
__global__ __launch_bounds__(256, 2) void k_kv(const unsigned short* __restrict__ xb,
                                               const unsigned short* __restrict__ Wt,
                                               const float* __restrict__ bias,
                                               unsigned short* __restrict__ K,
                                               unsigned short* __restrict__ V) {
    __shared__ __align__(16) unsigned short As[128 * 64];
    __shared__ __align__(16) unsigned short Bs[128 * 64];
    const int m0 = blockIdx.y * 128;           // tokens
    const int n0 = blockIdx.x * 128;           // KV cols
    const int plane = 1 + (n0 >> 10);          // 1=K, 2=V
    const int pc0 = n0 & 1023;
    const unsigned short* Wp = Wt + (unsigned)plane * 1048576u;
    const int wave = threadIdx.x >> 6, lane = threadIdx.x & 63;
    const int wm = (wave & 1) * 64, wn = (wave >> 1) * 64;
    const int lan15 = lane & 15, quad = lane >> 4;
    f32x4 acc[4][4] = {};
    const int slr = wave * 32 + (lane >> 3);
    const int scs = lane & 7;

    for (int kt = 0; kt < 16; kt++) {
        __syncthreads();
        for (int i = 0; i < 4; i++) {
            int lr = slr + i * 8;
            int c = scs ^ (lr & 7);
            async_ld16(xb + (unsigned)(m0 + lr) * 1024u + kt * 64 + c * 8,
                       (void*)(As + (wave * 32 + i * 8) * 64));
            async_ld16(Wp + (unsigned)(pc0 + lr) * 1024u + kt * 64 + c * 8,
                       (void*)(Bs + (wave * 32 + i * 8) * 64));
        }
        __syncthreads();
        for (int ks = 0; ks < 2; ks++) {
            bf16x8 af[4], bfr[4];
            int c0 = ks * 4 + quad;
            for (int tm = 0; tm < 4; tm++) {
                int row = wm + tm * 16 + lan15;
                af[tm] = *(const bf16x8*)(As + row * 64 + (c0 ^ (row & 7)) * 8);
            }
            for (int tn = 0; tn < 4; tn++) {
                int row = wn + tn * 16 + lan15;
                bfr[tn] = *(const bf16x8*)(Bs + row * 64 + (c0 ^ (row & 7)) * 8);
            }
            for (int tm = 0; tm < 4; tm++)
                for (int tn = 0; tn < 4; tn++)
                    acc[tm][tn] = mfma16(af[tm], bfr[tn], acc[tm][tn]);
        }
    }

    // epilogue: uniform class, packed 8B stores of 4 consecutive tokens
    const int batch = m0 >> 11;
    unsigned short* dst = (plane == 1) ? K : V;
    for (int tn = 0; tn < 4; tn++) {
        int cip = pc0 + wn + tn * 16 + lan15;       // col in plane
        int h = cip >> 6, d = cip & 63;
        float bv = bias[h * 192 + d * 3 + plane];
        unsigned kv_base = ((unsigned)(batch * 16 + h) * 64u + (unsigned)d) * 2048u;
        for (int tm = 0; tm < 4; tm++) {
            int rbase = m0 + wm + tm * 16 + quad * 4;
            unsigned token0 = (unsigned)(rbase & 2047);
            uint2 p;
            p.x = (unsigned)f2bf(acc[tm][tn][0] + bv) |
                  ((unsigned)f2bf(acc[tm][tn][1] + bv) << 16);
            p.y = (unsigned)f2bf(acc[tm][tn][2] + bv) |
                  ((unsigned)f2bf(acc[tm][tn][3] + bv) << 16);
            *(uint2*)(dst + kv_base + token0) = p;
        }
    }
}

// ---------------- k_attn4: redundant M = K^T V (async-staged), out = Q.M ----
// grid 512: bh = blockIdx & 63 (XCD swizzle), sub = blockIdx >> 6.
// Phase A: waves own 2x2 of M's 4x4 tile grid; K/V tiles staged via
// global_load_lds with mask-15 chunk swizzle (R1-proven pattern).
// M assembled in LDS (R2-proven 4-chunk swizzle). Phase B: out = Q.M.
__global__ __launch_bounds__(256) void k_attn4(const unsigned short* __restrict__ Kt,
                                               const unsigned short* __restrict__ Vt,
                                               const unsigned short* __restrict__ Qs,
                                               float* __restrict__ out) {
    __shared__ __align__(16) unsigned short Ks[64 * 128];   // 16KB [d][tok]
    __shared__ __align__(16) unsigned short Vs[64 * 128];   // 16KB [d][tok]
    __shared__ __align__(16) unsigned short Msb[64 * 64];   // 8KB [d2][d1]
    const int bh = blockIdx.x & 63, sub = blockIdx.x >> 6;
    const int b = bh >> 4, h = bh & 15;
    const int wave = threadIdx.x >> 6, lane = threadIdx.x & 63;
    const int lan15 = lane & 15, quad = lane >> 4;
    const unsigned base = (unsigned)bh * 131072u;
    const int mt0 = (wave & 1) * 2, nt0 = (wave >> 1) * 2;   // wave's 2x2 tiles
    const int slr = wave * 16 + (lane >> 4), scs = lane & 15;

    f32x4 macc[2][2] = {};
    for (int j = 0; j < 16; j++) {
        __syncthreads();
        for (int i = 0; i < 4; i++) {
            int lr = slr + i * 4;
            int c = scs ^ (lr & 15);
            async_ld16(Kt + base + (unsigned)lr * 2048u + j * 128 + c * 8,
                       (void*)(Ks + (wave * 16 + i * 4) * 128));
            async_ld16(Vt + base + (unsigned)lr * 2048u + j * 128 + c * 8,
                       (void*)(Vs + (wave * 16 + i * 4) * 128));
        }
        __syncthreads();
        for (int ks2 = 0; ks2 < 4; ks2++) {
            int c0 = ks2 * 4 + quad;
            bf16x8 ak[2], bv[2];
            for (int i = 0; i < 2; i++) {
                int row = (mt0 + i) * 16 + lan15;
                ak[i] = *(const bf16x8*)(Ks + row * 128 + (c0 ^ (row & 15)) * 8);
            }
            for (int i = 0; i < 2; i++) {
                int row = (nt0 + i) * 16 + lan15;
                bv[i] = *(const bf16x8*)(Vs + row * 128 + (c0 ^ (row & 15)) * 8);
            }
            for (int i = 0; i < 2; i++)
                for (int j2 = 0; j2 < 2; j2++)
                    macc[i][j2] = mfma16(ak[i], bv[j2], macc[i][j2]);
        }
    }
    // write M tiles: lane holds d1 = (mt0+i)*16 + quad*4 + r, d2 = (nt0+j2)*16+lan15
    for (int i = 0; i < 2; i++)
        for (int j2 = 0; j2 < 2; j2++) {
            int d2 = (nt0 + j2) * 16 + lan15;
            int c4 = ((mt0 + i) * 4 + quad) ^ (d2 & 15);
            uint2 p;
            p.x = (unsigned)f2bf(macc[i][j2][0]) | ((unsigned)f2bf(macc[i][j2][1]) << 16);
            p.y = (unsigned)f2bf(macc[i][j2][2]) | ((unsigned)f2bf(macc[i][j2][3]) << 16);
            *(uint2*)(Msb + d2 * 64 + c4 * 4) = p;
        }
    __syncthreads();

    // ---- phase B: out rows [sub*256 + wave*64, +64) = Q . M ----
    const int t0 = sub * 256 + wave * 64;
    f32x4 oacc[4][4] = {};
#pragma unroll
    for (int ks = 0; ks < 2; ks++) {
        bf16x8 af[4], bfr[4];
        for (int mt = 0; mt < 4; mt++) {
            int tok = t0 + mt * 16 + lan15;
            af[mt] = *(const bf16x8*)(Qs + (unsigned)b * 2097152u + (unsigned)tok * 1024u +
                                      h * 64 + ks * 32 + quad * 8);
        }
        for (int nt = 0; nt < 4; nt++) {
            int d2 = nt * 16 + lan15;
            int cA = ks * 8 + quad * 2;
            uint2 u0 = *(const uint2*)(Msb + d2 * 64 + ((cA) ^ (d2 & 15)) * 4);
            uint2 u1 = *(const uint2*)(Msb + d2 * 64 + ((cA + 1) ^ (d2 & 15)) * 4);
            union { uint4 u; bf16x8 v; } cv;
            cv.u.x = u0.x; cv.u.y = u0.y; cv.u.z = u1.x; cv.u.w = u1.y;
            bfr[nt] = cv.v;
        }
        for (int mt = 0; mt < 4; mt++)
            for (int nt = 0; nt < 4; nt++)
                oacc[mt][nt] = mfma16(af[mt], bfr[nt], oacc[mt][nt]);
    }
    for (int mt = 0; mt < 4; mt++)
        for (int nt = 0; nt < 4; nt++)
            for (int r = 0; r < 4; r++)
                out[base + (unsigned)(t0 + mt * 16 + quad * 4 + r) * 64u + nt * 16 + lan15] =
                    oacc[mt][nt][r];
}

extern "C" void kernel_launch(void* const* d_in, const int* in_sizes, int n_in,
                              void* d_out, int out_size, void* d_ws, size_t ws_size,
                              hipStream_t stream) {
    const float* x = (const float*)d_in[0];
    const float* W = (const float*)d_in[1];
    const float* b = (const float*)d_in[2];
    float* out = (float*)d_out;

    unsigned short* xb = (unsigned short*)d_ws;  // 8,388,608  [8192][1024] bf16
    unsigned short* Wt = xb + 8388608;           // 3,145,728  [3][1024][1024] bf16
    unsigned short* Qs = Wt + 3145728;           // 8,388,608  [4][2048][1024] bf16 (*32,+bias)
    unsigned short* Kt = Qs + 8388608;           // 8,388,608  [bh][d][n] bf16 (+bias)
    unsigned short* Vt = Kt + 8388608;           // 8,388,608  [bh][d][n] bf16 (+bias)
    // total: 73,400,320 bytes (known-safe)

    k_prep<<<4864, 256, 0, stream>>>(x, W, xb, Wt);
    k_q<<<dim3(8, 64), 256, 0, stream>>>(Wt, xb, b, Qs);
    k_kv<<<dim3(16, 64), 256, 0, stream>>>(xb, Wt, b, Kt, Vt);
    k_attn4<<<512, 256, 0, stream>>>(Kt, Vt, Qs, out);
}